// Round 1
// baseline (100.307 us; speedup 1.0000x reference)
//
#include <hip/hip_runtime.h>
#include <hip/hip_bf16.h>

#define TT 256   // sequence length
#define CE 384   // embed
#define HD 64    // head size

typedef __attribute__((ext_vector_type(8))) short short8v;
typedef __attribute__((ext_vector_type(4))) float float4v;
typedef __attribute__((ext_vector_type(4))) unsigned int uint4v;
typedef __attribute__((ext_vector_type(4))) unsigned short ushort4v;

#define SCALE 0.05103103630798287f  // 384^-0.5 (reference scales by C, not H)

__device__ __forceinline__ unsigned short f2bf(float f) {
    unsigned int u = __float_as_uint(f);
    unsigned int r = (u + 0x7FFFu + ((u >> 16) & 1u)) >> 16;  // RNE
    return (unsigned short)r;
}
__device__ __forceinline__ unsigned int pk2(float a, float b) {
    return (unsigned int)f2bf(a) | ((unsigned int)f2bf(b) << 16);
}

// Swizzled LDS addressing (16B-chunk XOR of row bits -> conflict-free frag reads)
// rows of 64 bf16 (128 B)
__device__ __forceinline__ int adr8(int row, int col) {
    return row * 128 + ((((col >> 3) ^ (row & 7)) & 7) << 4) + ((col & 7) << 1);
}
// rows of 128 bf16 (256 B)
__device__ __forceinline__ int adr16(int row, int col) {
    return row * 256 + ((((col >> 3) ^ (row & 15)) & 15) << 4) + ((col & 7) << 1);
}

// ---------------- kernel 0: weight transpose + bf16 convert -----------------
// Wt[w][h][c] (bf16)  <-  W[c][h] (f32), w in {0:K,1:Q,2:V}
__global__ void wprep(const float* __restrict__ Wk, const float* __restrict__ Wq,
                      const float* __restrict__ Wv, unsigned short* __restrict__ Wt) {
    int idx = blockIdx.x * 256 + threadIdx.x;
    if (idx >= 3 * HD * CE) return;
    int w = idx / (HD * CE);
    int rem = idx - w * (HD * CE);
    int h = rem / CE;
    int c = rem - h * CE;
    const float* W = (w == 0) ? Wk : (w == 1) ? Wq : Wv;
    Wt[idx] = f2bf(W[c * HD + h]);
}

// ---------------- kernel 1: fused QKV projection (per-batch GEMM) -----------
// block = 1024 threads (16 waves), one batch: X(256x384) @ [Wk|Wq|Wv](384x192)
// wave (w&7) owns rows (w&7)*32..+32; (w>>3) owns col-half of 96.
// Writes Kb[b][t][h], Qb[b][t][h], Vt[b][h][t] (transposed!) as bf16.
__global__ __launch_bounds__(1024)
void qkv(const float* __restrict__ X, const unsigned short* __restrict__ Wt,
         unsigned short* __restrict__ Kb, unsigned short* __restrict__ Qb,
         unsigned short* __restrict__ Vt) {
    __shared__ char lds[57344];
    char* Xs = lds;            // 256 rows x 128B (256x64 bf16, adr8)
    char* Ws = lds + 32768;    // 192 rows x 128B (192x64 bf16, adr8)
    const int b = blockIdx.x;
    const int tid = threadIdx.x;
    const int w = tid >> 6, l = tid & 63;
    const int l15 = l & 15, lq = l >> 4;
    const int wr = (w & 7) * 32;
    const int nh = w >> 3;

    const float4v fzero = {0.f, 0.f, 0.f, 0.f};
    float4v acc[2][6];
    #pragma unroll
    for (int i = 0; i < 2; ++i)
        #pragma unroll
        for (int j = 0; j < 6; ++j) acc[i][j] = fzero;

    const float* Xb = X + (long)b * TT * CE;

    for (int kk = 0; kk < CE; kk += 64) {
        __syncthreads();
        // stage X chunk 256x64 f32 -> bf16 (2048 16B chunks)
        #pragma unroll
        for (int j = 0; j < 2; ++j) {
            int ci = j * 1024 + tid;
            int t = ci >> 3, k8 = ci & 7;
            const float* src = Xb + t * CE + kk + k8 * 8;
            float4 x0 = *(const float4*)src;
            float4 x1 = *(const float4*)(src + 4);
            uint4v p = {pk2(x0.x, x0.y), pk2(x0.z, x0.w), pk2(x1.x, x1.y), pk2(x1.z, x1.w)};
            *(uint4v*)(Xs + t * 128 + (((k8 ^ (t & 7)) & 7) << 4)) = p;
        }
        // stage W chunk 192x64 bf16 (1536 chunks)
        for (int ci = tid; ci < 1536; ci += 1024) {
            int n = ci >> 3, k8 = ci & 7;
            uint4v p = *(const uint4v*)(Wt + n * CE + kk + k8 * 8);
            *(uint4v*)(Ws + n * 128 + (((k8 ^ (n & 7)) & 7) << 4)) = p;
        }
        __syncthreads();
        #pragma unroll
        for (int ks = 0; ks < 2; ++ks) {
            short8v a0 = *(const short8v*)(Xs + adr8(wr + l15,      ks * 32 + lq * 8));
            short8v a1 = *(const short8v*)(Xs + adr8(wr + 16 + l15, ks * 32 + lq * 8));
            #pragma unroll
            for (int nt = 0; nt < 6; ++nt) {
                short8v bb = *(const short8v*)(Ws + adr8(nh * 96 + nt * 16 + l15, ks * 32 + lq * 8));
                acc[0][nt] = __builtin_amdgcn_mfma_f32_16x16x32_bf16(a0, bb, acc[0][nt], 0, 0, 0);
                acc[1][nt] = __builtin_amdgcn_mfma_f32_16x16x32_bf16(a1, bb, acc[1][nt], 0, 0, 0);
            }
        }
    }

    // epilogue: C tile (t,n): t = wr + rt*16 + lq*4 + r, n = nh*96 + nt*16 + l15
    #pragma unroll
    for (int rt = 0; rt < 2; ++rt) {
        #pragma unroll
        for (int nt = 0; nt < 6; ++nt) {
            int n = nh * 96 + nt * 16 + l15;
            int t0 = wr + rt * 16 + lq * 4;
            if (n < 64) {          // K, row-major
                #pragma unroll
                for (int r = 0; r < 4; ++r)
                    Kb[((long)b * TT + t0 + r) * HD + n] = f2bf(acc[rt][nt][r]);
            } else if (n < 128) {  // Q, row-major
                int h = n - 64;
                #pragma unroll
                for (int r = 0; r < 4; ++r)
                    Qb[((long)b * TT + t0 + r) * HD + h] = f2bf(acc[rt][nt][r]);
            } else {               // V, transposed [b][h][t], 4 consecutive t -> 8B store
                int h = n - 128;
                ushort4v pv;
                pv[0] = f2bf(acc[rt][nt][0]);
                pv[1] = f2bf(acc[rt][nt][1]);
                pv[2] = f2bf(acc[rt][nt][2]);
                pv[3] = f2bf(acc[rt][nt][3]);
                *(ushort4v*)(Vt + ((long)b * HD + h) * TT + t0) = pv;
            }
        }
    }
}

// ---------------- kernel 2: attention (query-axis softmax) ------------------
// one block (512 thr, 8 waves) per batch. Z = K Q^T so softmax axis (t) is the
// MFMA column index -> 16-lane shfl_xor reduction. O = W V via LDS round-trip.
__global__ __launch_bounds__(512)
void attn(const unsigned short* __restrict__ Kb, const unsigned short* __restrict__ Qb,
          const unsigned short* __restrict__ Vt, float* __restrict__ out) {
    extern __shared__ char lds[];
    char* Qs  = lds;            // 32768: 256x64 bf16, adr8
    char* Ks  = lds + 32768;    // 16384: 128x64 bf16, adr8
    char* Vts = lds + 49152;    // 16384: 64x128 bf16 (V^T slab), adr16
    char* Wts = lds + 65536;    // 65536: 256x128 bf16 (weights), adr16

    const int b = blockIdx.x;
    const int tid = threadIdx.x;
    const int w = tid >> 6, l = tid & 63;
    const int l15 = l & 15, lq = l >> 4;

    // stage Q (256x64)
    #pragma unroll
    for (int j = 0; j < 4; ++j) {
        int ci = j * 512 + tid;
        int t = ci >> 3, k8 = ci & 7;
        uint4v p = *(const uint4v*)(Qb + ((long)b * TT + t) * HD + k8 * 8);
        *(uint4v*)(Qs + t * 128 + (((k8 ^ (t & 7)) & 7) << 4)) = p;
    }

    const float4v fzero = {0.f, 0.f, 0.f, 0.f};
    float4v o[2][4];
    #pragma unroll
    for (int i = 0; i < 2; ++i)
        #pragma unroll
        for (int j = 0; j < 4; ++j) o[i][j] = fzero;

    for (int sb = 0; sb < 2; ++sb) {
        const int s0 = sb * 128;
        __syncthreads();   // previous O-GEMM done before restage
        #pragma unroll
        for (int j = 0; j < 2; ++j) {   // K rows s0..s0+128
            int ci = j * 512 + tid;
            int r = ci >> 3, k8 = ci & 7;
            uint4v p = *(const uint4v*)(Kb + ((long)b * TT + s0 + r) * HD + k8 * 8);
            *(uint4v*)(Ks + r * 128 + (((k8 ^ (r & 7)) & 7) << 4)) = p;
        }
        #pragma unroll
        for (int j = 0; j < 2; ++j) {   // V^T slab [64][s0..s0+128]
            int ci = j * 512 + tid;
            int h = ci >> 4, s8 = ci & 15;
            uint4v p = *(const uint4v*)(Vt + ((long)b * HD + h) * TT + s0 + s8 * 8);
            *(uint4v*)(Vts + h * 256 + (((s8 ^ (h & 15)) & 15) << 4)) = p;
        }
        __syncthreads();

        // Z = K Q^T for wave's 16 s-rows; Z[s][t], t = col
        float4v z[16];
        #pragma unroll
        for (int tt = 0; tt < 16; ++tt) z[tt] = fzero;
        #pragma unroll
        for (int ks = 0; ks < 2; ++ks) {
            short8v ak = *(const short8v*)(Ks + adr8(w * 16 + l15, ks * 32 + lq * 8));
            #pragma unroll
            for (int tt = 0; tt < 16; ++tt) {
                short8v bq = *(const short8v*)(Qs + adr8(tt * 16 + l15, ks * 32 + lq * 8));
                z[tt] = __builtin_amdgcn_mfma_f32_16x16x32_bf16(ak, bq, z[tt], 0, 0, 0);
            }
        }

        // masked scale + softmax over t (per s-row: lanes sharing lq, 16 t per tile)
        float inv[4];
        const int sgb = s0 + w * 16 + lq * 4;
        #pragma unroll
        for (int r = 0; r < 4; ++r) {
            const int s = sgb + r;
            float mm = -1e30f;
            #pragma unroll
            for (int tt = 0; tt < 16; ++tt) {
                int t = tt * 16 + l15;
                float v = (t >= s) ? z[tt][r] * SCALE : -1e30f;  // causal: keep t >= s
                z[tt][r] = v;
                mm = fmaxf(mm, v);
            }
            mm = fmaxf(mm, __shfl_xor(mm, 1));
            mm = fmaxf(mm, __shfl_xor(mm, 2));
            mm = fmaxf(mm, __shfl_xor(mm, 4));
            mm = fmaxf(mm, __shfl_xor(mm, 8));
            float ss = 0.f;
            #pragma unroll
            for (int tt = 0; tt < 16; ++tt) {
                float p = (z[tt][r] > -1e29f) ? __expf(z[tt][r] - mm) : 0.f;
                z[tt][r] = p;
                ss += p;
            }
            ss += __shfl_xor(ss, 1);
            ss += __shfl_xor(ss, 2);
            ss += __shfl_xor(ss, 4);
            ss += __shfl_xor(ss, 8);
            inv[r] = 1.f / ss;
        }

        // write normalized weights W[t][s_local] (bf16) -- 4 consecutive s per lane
        #pragma unroll
        for (int tt = 0; tt < 16; ++tt) {
            int t = tt * 16 + l15;
            int col = w * 16 + lq * 4;
            ushort4v pw;
            pw[0] = f2bf(z[tt][0] * inv[0]);
            pw[1] = f2bf(z[tt][1] * inv[1]);
            pw[2] = f2bf(z[tt][2] * inv[2]);
            pw[3] = f2bf(z[tt][3] * inv[3]);
            *(ushort4v*)(Wts + t * 256 + ((((col >> 3) ^ (t & 15)) & 15) << 4) + ((col & 7) << 1)) = pw;
        }
        __syncthreads();

        // O += W V  (wave owns t rows w*32..+32, all 64 h)
        #pragma unroll
        for (int ks = 0; ks < 4; ++ks) {
            short8v aw0 = *(const short8v*)(Wts + adr16(w * 32 + l15,      ks * 32 + lq * 8));
            short8v aw1 = *(const short8v*)(Wts + adr16(w * 32 + 16 + l15, ks * 32 + lq * 8));
            #pragma unroll
            for (int ht = 0; ht < 4; ++ht) {
                short8v bv = *(const short8v*)(Vts + adr16(ht * 16 + l15, ks * 32 + lq * 8));
                o[0][ht] = __builtin_amdgcn_mfma_f32_16x16x32_bf16(aw0, bv, o[0][ht], 0, 0, 0);
                o[1][ht] = __builtin_amdgcn_mfma_f32_16x16x32_bf16(aw1, bv, o[1][ht], 0, 0, 0);
            }
        }
    }

    // store O (f32, coalesced 64B per 16-lane group)
    #pragma unroll
    for (int rt = 0; rt < 2; ++rt)
        #pragma unroll
        for (int ht = 0; ht < 4; ++ht) {
            int t0 = w * 32 + rt * 16 + lq * 4;
            int h = ht * 16 + l15;
            #pragma unroll
            for (int r = 0; r < 4; ++r)
                out[((long)b * TT + t0 + r) * HD + h] = o[rt][ht][r];
        }
}

// ---------------------------------------------------------------------------
extern "C" void kernel_launch(void* const* d_in, const int* in_sizes, int n_in,
                              void* d_out, int out_size, void* d_ws, size_t ws_size,
                              hipStream_t stream) {
    const float* X  = (const float*)d_in[0];
    const float* Wk = (const float*)d_in[1];
    const float* Wq = (const float*)d_in[2];
    const float* Wv = (const float*)d_in[3];
    float* out = (float*)d_out;

    char* ws = (char*)d_ws;
    unsigned short* Wt = (unsigned short*)ws;                              // 147456 B
    unsigned short* Kb = (unsigned short*)(ws + 147456);                   // 16 MiB
    unsigned short* Qb = (unsigned short*)(ws + 147456 + 16777216L);       // 16 MiB
    unsigned short* Vt = (unsigned short*)(ws + 147456 + 2 * 16777216L);   // 16 MiB

    // allow 128 KiB dynamic LDS for attn (deterministic, capture-safe host call)
    (void)hipFuncSetAttribute(reinterpret_cast<const void*>(attn),
                              hipFuncAttributeMaxDynamicSharedMemorySize, 131072);

    wprep<<<288, 256, 0, stream>>>(Wk, Wq, Wv, Wt);
    qkv<<<512, 1024, 0, stream>>>(X, Wt, Kb, Qb, Vt);
    attn<<<512, 512, 131072, stream>>>(Kb, Qb, Vt, out);
}

// Round 3
// 73.859 us; speedup vs baseline: 1.3581x; 1.3581x over previous
//
#include <hip/hip_runtime.h>
#include <hip/hip_bf16.h>

#define TT 256   // sequence length
#define CE 384   // embed
#define HD 64    // head size

typedef __attribute__((ext_vector_type(8))) short short8v;
typedef __attribute__((ext_vector_type(4))) float float4v;
typedef __attribute__((ext_vector_type(4))) unsigned int uint4v;
typedef __attribute__((ext_vector_type(4))) unsigned short ushort4v;

#define SCALE 0.05103103630798287f  // 384^-0.5 (reference scales by C, not H)

__device__ __forceinline__ unsigned short f2bf(float f) {
    unsigned int u = __float_as_uint(f);
    unsigned int r = (u + 0x7FFFu + ((u >> 16) & 1u)) >> 16;  // RNE
    return (unsigned short)r;
}
__device__ __forceinline__ unsigned int pk2(float a, float b) {
    return (unsigned int)f2bf(a) | ((unsigned int)f2bf(b) << 16);
}

// Swizzled LDS addressing (16B-chunk XOR of row bits -> conflict-free frag reads)
// rows of 64 bf16 (128 B)
__device__ __forceinline__ int adr8(int row, int col) {
    return row * 128 + ((((col >> 3) ^ (row & 7)) & 7) << 4) + ((col & 7) << 1);
}
// rows of 128 bf16 (256 B)
__device__ __forceinline__ int adr16(int row, int col) {
    return row * 256 + ((((col >> 3) ^ (row & 15)) & 15) << 4) + ((col & 7) << 1);
}

// ---------------- kernel 0: weight transpose + bf16 convert -----------------
// Wt[w][h][c] (bf16)  <-  W[c][h] (f32), w in {0:K,1:Q,2:V}
__global__ void wprep(const float* __restrict__ Wk, const float* __restrict__ Wq,
                      const float* __restrict__ Wv, unsigned short* __restrict__ Wt) {
    int idx = blockIdx.x * 256 + threadIdx.x;
    if (idx >= 3 * HD * CE) return;
    int w = idx / (HD * CE);
    int rem = idx - w * (HD * CE);
    int h = rem / CE;
    int c = rem - h * CE;
    const float* W = (w == 0) ? Wk : (w == 1) ? Wq : Wv;
    Wt[idx] = f2bf(W[c * HD + h]);
}

// ---------------- fused kernel: QKV projection + attention per batch --------
// 512 threads (8 waves), one batch per block. LDS (160 KiB):
//   Qs   @ 0      : 32 KiB  256x64 bf16 (adr8)
//   Ks   @ 32768  : 32 KiB  256x64 bf16 (adr8)
//   Vts0 @ 65536  : 16 KiB  64x128 bf16 (adr16), s = 0..127  (V transposed)
//   Vts1 @ 81920  : 16 KiB  64x128 bf16 (adr16), s = 128..255
//   Wts  @ 98304  : 64 KiB  256x128 bf16 (adr16) softmax weights
//                   -- time-shared in phase 1 as X(32K)+W(24K) staging scratch
__global__ __launch_bounds__(512, 2)
void fused(const float* __restrict__ X, const unsigned short* __restrict__ Wt,
           float* __restrict__ out) {
    extern __shared__ char lds[];
    char* Qs   = lds;
    char* Ks   = lds + 32768;
    char* Vts0 = lds + 65536;
    char* Wts  = lds + 98304;
    char* Xs   = Wts;             // phase-1 scratch
    char* Ws   = Wts + 32768;     // phase-1 scratch (24 KiB)

    const int b = blockIdx.x;
    const int tid = threadIdx.x;
    const int w = tid >> 6, l = tid & 63;
    const int l15 = l & 15, lq = l >> 4;

    // ---------------- phase 1: QKV = X @ [Wk|Wq|Wv]  (256x192, K=384) -------
    // wave: tg = w&3 owns t-rows tg*64..+64 (4x16 tiles); nh = w>>2 owns 96 n-cols
    const int tg = w & 3, nh = w >> 2;

    const float4v fzero = {0.f, 0.f, 0.f, 0.f};
    float4v acc[4][6];
    #pragma unroll
    for (int i = 0; i < 4; ++i)
        #pragma unroll
        for (int j = 0; j < 6; ++j) acc[i][j] = fzero;

    const float* Xb = X + (long)b * TT * CE;

    // per-thread staging slots: 4 X-chunks (16B bf16 each from 32B f32), 3 W-chunks
    int xt[4], xk[4], wn[3], wk[3];
    #pragma unroll
    for (int j = 0; j < 4; ++j) { int ci = j * 512 + tid; xt[j] = ci >> 3; xk[j] = ci & 7; }
    #pragma unroll
    for (int j = 0; j < 3; ++j) { int ci = j * 512 + tid; wn[j] = ci >> 3; wk[j] = ci & 7; }

    float4 xr[4][2];
    uint4v wreg[3];

    auto load_chunk = [&](int kk) {
        #pragma unroll
        for (int j = 0; j < 4; ++j) {
            const float* src = Xb + xt[j] * CE + kk + xk[j] * 8;
            xr[j][0] = *(const float4*)src;
            xr[j][1] = *(const float4*)(src + 4);
        }
        #pragma unroll
        for (int j = 0; j < 3; ++j)
            wreg[j] = *(const uint4v*)(Wt + wn[j] * CE + kk + wk[j] * 8);
    };
    auto store_chunk = [&]() {
        #pragma unroll
        for (int j = 0; j < 4; ++j) {
            uint4v p = {pk2(xr[j][0].x, xr[j][0].y), pk2(xr[j][0].z, xr[j][0].w),
                        pk2(xr[j][1].x, xr[j][1].y), pk2(xr[j][1].z, xr[j][1].w)};
            *(uint4v*)(Xs + xt[j] * 128 + (((xk[j] ^ (xt[j] & 7)) & 7) << 4)) = p;
        }
        #pragma unroll
        for (int j = 0; j < 3; ++j)
            *(uint4v*)(Ws + wn[j] * 128 + (((wk[j] ^ (wn[j] & 7)) & 7) << 4)) = wreg[j];
    };

    load_chunk(0);
    for (int kc = 0; kc < 6; ++kc) {
        __syncthreads();           // scratch free (prev MFMA reads done)
        store_chunk();
        if (kc < 5) load_chunk((kc + 1) * 64);   // in flight across the MFMA phase
        __syncthreads();
        #pragma unroll
        for (int ks = 0; ks < 2; ++ks) {
            short8v a[4];
            #pragma unroll
            for (int rt = 0; rt < 4; ++rt)
                a[rt] = *(const short8v*)(Xs + adr8(tg * 64 + rt * 16 + l15, ks * 32 + lq * 8));
            #pragma unroll
            for (int nt = 0; nt < 6; ++nt) {
                short8v bb = *(const short8v*)(Ws + adr8(nh * 96 + nt * 16 + l15, ks * 32 + lq * 8));
                #pragma unroll
                for (int rt = 0; rt < 4; ++rt)
                    acc[rt][nt] = __builtin_amdgcn_mfma_f32_16x16x32_bf16(a[rt], bb, acc[rt][nt], 0, 0, 0);
            }
        }
    }

    __syncthreads();   // all MFMA reads of Xs/Ws scratch done before phase 2 reuses Wts

    // epilogue: write K,Q into Qs/Ks (adr8), V transposed into Vts (adr16)
    #pragma unroll
    for (int rt = 0; rt < 4; ++rt) {
        const int t0 = tg * 64 + rt * 16 + lq * 4;
        #pragma unroll
        for (int nt = 0; nt < 6; ++nt) {
            const int n = nh * 96 + nt * 16 + l15;
            if (n < 64) {              // K
                #pragma unroll
                for (int r = 0; r < 4; ++r)
                    *(unsigned short*)(Ks + adr8(t0 + r, n)) = f2bf(acc[rt][nt][r]);
            } else if (n < 128) {      // Q
                const int h = n - 64;
                #pragma unroll
                for (int r = 0; r < 4; ++r)
                    *(unsigned short*)(Qs + adr8(t0 + r, h)) = f2bf(acc[rt][nt][r]);
            } else {                   // V -> transposed [h][s]
                const int h = n - 128;
                char* vbase = Vts0 + (t0 >> 7) * 16384;
                const int sl = t0 & 127;
                ushort4v pv;
                pv[0] = f2bf(acc[rt][nt][0]);
                pv[1] = f2bf(acc[rt][nt][1]);
                pv[2] = f2bf(acc[rt][nt][2]);
                pv[3] = f2bf(acc[rt][nt][3]);
                *(ushort4v*)(vbase + adr16(h, sl)) = pv;
            }
        }
    }

    // ---------------- phase 2: attention ------------------------------------
    float4v o[2][4];
    #pragma unroll
    for (int i = 0; i < 2; ++i)
        #pragma unroll
        for (int j = 0; j < 4; ++j) o[i][j] = fzero;

    for (int sb = 0; sb < 2; ++sb) {
        const int s0 = sb * 128;
        __syncthreads();   // K/Q/V slabs ready (sb=0) / prev PV done, Wts free (sb=1)

        // Z = K Q^T for wave's 16 s-rows; Z[s][t], t = col (full t range)
        float4v z[16];
        #pragma unroll
        for (int tt = 0; tt < 16; ++tt) z[tt] = fzero;
        #pragma unroll
        for (int ks = 0; ks < 2; ++ks) {
            short8v ak = *(const short8v*)(Ks + adr8(s0 + w * 16 + l15, ks * 32 + lq * 8));
            #pragma unroll
            for (int tt = 0; tt < 16; ++tt) {
                short8v bq = *(const short8v*)(Qs + adr8(tt * 16 + l15, ks * 32 + lq * 8));
                z[tt] = __builtin_amdgcn_mfma_f32_16x16x32_bf16(ak, bq, z[tt], 0, 0, 0);
            }
        }

        // masked scale + softmax over t (query axis): lanes sharing lq hold the row
        float inv[4];
        const int sgb = s0 + w * 16 + lq * 4;
        #pragma unroll
        for (int r = 0; r < 4; ++r) {
            const int s = sgb + r;
            float mm = -1e30f;
            #pragma unroll
            for (int tt = 0; tt < 16; ++tt) {
                int t = tt * 16 + l15;
                float v = (t >= s) ? z[tt][r] * SCALE : -1e30f;  // causal: keep t >= s
                z[tt][r] = v;
                mm = fmaxf(mm, v);
            }
            mm = fmaxf(mm, __shfl_xor(mm, 1));
            mm = fmaxf(mm, __shfl_xor(mm, 2));
            mm = fmaxf(mm, __shfl_xor(mm, 4));
            mm = fmaxf(mm, __shfl_xor(mm, 8));
            float ss = 0.f;
            #pragma unroll
            for (int tt = 0; tt < 16; ++tt) {
                float p = (z[tt][r] > -1e29f) ? __expf(z[tt][r] - mm) : 0.f;
                z[tt][r] = p;
                ss += p;
            }
            ss += __shfl_xor(ss, 1);
            ss += __shfl_xor(ss, 2);
            ss += __shfl_xor(ss, 4);
            ss += __shfl_xor(ss, 8);
            inv[r] = 1.f / ss;
        }

        // write normalized weights W[t][s_local] (bf16, adr16-swizzled)
        #pragma unroll
        for (int tt = 0; tt < 16; ++tt) {
            int t = tt * 16 + l15;
            int col = w * 16 + lq * 4;
            ushort4v pw;
            pw[0] = f2bf(z[tt][0] * inv[0]);
            pw[1] = f2bf(z[tt][1] * inv[1]);
            pw[2] = f2bf(z[tt][2] * inv[2]);
            pw[3] = f2bf(z[tt][3] * inv[3]);
            *(ushort4v*)(Wts + adr16(t, col)) = pw;
        }
        __syncthreads();

        // O += W V   (wave owns t rows w*32..+32, all 64 h)
        const char* vb = Vts0 + sb * 16384;
        #pragma unroll
        for (int ks = 0; ks < 4; ++ks) {
            short8v aw0 = *(const short8v*)(Wts + adr16(w * 32 + l15,      ks * 32 + lq * 8));
            short8v aw1 = *(const short8v*)(Wts + adr16(w * 32 + 16 + l15, ks * 32 + lq * 8));
            #pragma unroll
            for (int ht = 0; ht < 4; ++ht) {
                short8v bv = *(const short8v*)(vb + adr16(ht * 16 + l15, ks * 32 + lq * 8));
                o[0][ht] = __builtin_amdgcn_mfma_f32_16x16x32_bf16(aw0, bv, o[0][ht], 0, 0, 0);
                o[1][ht] = __builtin_amdgcn_mfma_f32_16x16x32_bf16(aw1, bv, o[1][ht], 0, 0, 0);
            }
        }
    }

    // store O (f32, coalesced 64B per 16-lane group)
    #pragma unroll
    for (int rt = 0; rt < 2; ++rt)
        #pragma unroll
        for (int ht = 0; ht < 4; ++ht) {
            int t0 = w * 32 + rt * 16 + lq * 4;
            int h = ht * 16 + l15;
            #pragma unroll
            for (int r = 0; r < 4; ++r)
                out[((long)b * TT + t0 + r) * HD + h] = o[rt][ht][r];
        }
}

// ---------------------------------------------------------------------------
extern "C" void kernel_launch(void* const* d_in, const int* in_sizes, int n_in,
                              void* d_out, int out_size, void* d_ws, size_t ws_size,
                              hipStream_t stream) {
    const float* X  = (const float*)d_in[0];
    const float* Wk = (const float*)d_in[1];
    const float* Wq = (const float*)d_in[2];
    const float* Wv = (const float*)d_in[3];
    float* out = (float*)d_out;

    unsigned short* Wt = (unsigned short*)d_ws;   // 3*64*384 bf16 = 147456 B

    (void)hipFuncSetAttribute(reinterpret_cast<const void*>(fused),
                              hipFuncAttributeMaxDynamicSharedMemorySize, 163840);

    wprep<<<288, 256, 0, stream>>>(Wk, Wq, Wv, Wt);
    fused<<<512, 512, 163840, stream>>>(X, Wt, out);
}